// Round 1
// baseline (510.893 us; speedup 1.0000x reference)
//
#include <hip/hip_runtime.h>
#include <hip/hip_bf16.h>
#include <hip/hip_fp16.h>
#include <math.h>

#define Bn 16
#define Nn 2048
#define Cn 128

typedef __attribute__((ext_vector_type(8))) short bf16x8;   // 8 bf16 = 4 VGPRs
typedef __attribute__((ext_vector_type(4))) float f32x4;

// 0.5 / (sqrt(128) * 1.5)  -- folds symmetrization 0.5 and temperature
constexpr float SCALE = 0.029462782549439476f;
constexpr float SHIFT = 4.0f;  // fixed softmax shift; logits bounded well below this +88

// LDS row stride in bf16 elems: 128 + 8 pad -> 272 B = 68 dwords == 4 (mod 32)
// kills the 16-way bank conflict of the unpadded 256 B (== 0 mod 32) stride.
#define LDS_STRIDE 136

__device__ __forceinline__ const bf16x8* as_frag(const __hip_bfloat16* p){
    return reinterpret_cast<const bf16x8*>(p);
}

// --- fused prep: combined bias (fp16) for all blocks; first 64 blocks also
//     transpose W [d][c] -> WT [c][d] so the projection kernel reads coalesced.
__global__ __launch_bounds__(256) void prep_kernel(
    const float* __restrict__ A, const float* __restrict__ M, __half* __restrict__ CB,
    const float* __restrict__ Wq, const float* __restrict__ Wk,
    float* __restrict__ WqT, float* __restrict__ WkT)
{
    size_t idx = (size_t)blockIdx.x * 256 + threadIdx.x;
    int n = (int)(idx >> 11), m = (int)(idx & (Nn-1));
    float a = A[idx];
    float mm = M[idx];
    float v = (mm <= 0.0f || n == m) ? -INFINITY : a;
    CB[idx] = __float2half(v);
    if (blockIdx.x < 64) {
        int widx = (int)idx;            // 0..16383
        int d = widx >> 7, c = widx & 127;
        WqT[c*Cn + d] = Wq[widx];
        WkT[c*Cn + d] = Wk[widx];
    }
}

// --- Q/K projection: fp32 accumulate, bf16 store. 32 rows per block. ---
__global__ __launch_bounds__(256) void qk_kernel(
    const float* __restrict__ H, const float* __restrict__ WqT, const float* __restrict__ WkT,
    __hip_bfloat16* __restrict__ Qb, __hip_bfloat16* __restrict__ Kb)
{
    __shared__ __align__(16) float Hs[32*Cn];
    const int t = threadIdx.x;
    const size_t row0 = (size_t)blockIdx.x * 32;
    const float4* src = reinterpret_cast<const float4*>(H + row0*Cn);
    float4* dst = reinterpret_cast<float4*>(Hs);
    #pragma unroll
    for (int i = 0; i < 4; i++) dst[i*256 + t] = src[i*256 + t];
    __syncthreads();
    const int d = t & 127, rh = t >> 7;
    float accq[16], acck[16];
    #pragma unroll
    for (int r = 0; r < 16; r++){ accq[r] = 0.f; acck[r] = 0.f; }
    for (int cb = 0; cb < Cn; cb += 4){
        float wq[4], wk[4];
        #pragma unroll
        for (int j = 0; j < 4; j++){ wq[j] = WqT[(cb+j)*Cn + d]; wk[j] = WkT[(cb+j)*Cn + d]; }
        #pragma unroll
        for (int r = 0; r < 16; r++){
            float4 h = *reinterpret_cast<const float4*>(&Hs[(rh*16+r)*Cn + cb]);
            accq[r] += h.x*wq[0] + h.y*wq[1] + h.z*wq[2] + h.w*wq[3];
            acck[r] += h.x*wk[0] + h.y*wk[1] + h.z*wk[2] + h.w*wk[3];
        }
    }
    #pragma unroll
    for (int r = 0; r < 16; r++){
        size_t row = row0 + rh*16 + r;
        Qb[row*Cn + d] = __float2bfloat16(accq[r]);
        Kb[row*Cn + d] = __float2bfloat16(acck[r]);
    }
}

// --- single compute pass: sym logits via MFMA; writes UNNORMALIZED e to out
//     and reciprocal row sums to rowsum. (Replaces the old 2-pass recompute.)
// block = 256 threads = 4 waves; block tile = 64 rows (16/wave) x all 2048 cols.
__global__ __launch_bounds__(256) void attn_e_kernel(
    const __hip_bfloat16* __restrict__ Qb, const __hip_bfloat16* __restrict__ Kb,
    const __half* __restrict__ CB, float* __restrict__ rowsum, float* __restrict__ out)
{
    __shared__ __align__(16) __hip_bfloat16 Ks_s[64*LDS_STRIDE];
    __shared__ __align__(16) __hip_bfloat16 Qs_s[64*LDS_STRIDE];
    const int t = threadIdx.x;
    const int wave = t >> 6, lane = t & 63;
    const int q = lane >> 4, lc = lane & 15;
    const int batch = blockIdx.y;
    const int n0 = blockIdx.x * 64;
    const size_t rbase = (size_t)batch * Nn;

    // A-operand fragments for this wave's 16 rows: lane holds row (lc), k = ks*32 + q*8..+7
    const int nA = n0 + wave*16 + lc;
    bf16x8 aQ[4], aK[4];
    #pragma unroll
    for (int ks = 0; ks < 4; ks++){
        aQ[ks] = *as_frag(Qb + (rbase + nA)*Cn + ks*32 + q*8);
        aK[ks] = *as_frag(Kb + (rbase + nA)*Cn + ks*32 + q*8);
    }

    int nout[4];
    #pragma unroll
    for (int r = 0; r < 4; r++) nout[r] = n0 + wave*16 + q*4 + r;  // C/D row = q*4+reg

    float sumacc[4] = {0.f,0.f,0.f,0.f};

    for (int mc = 0; mc < Nn/64; mc++){
        __syncthreads();   // prev iter's LDS reads done before overwrite
        {   // stage 64-col tile of K and Q: 1024 16-B chunks each, 4 per thread.
            // global reads coalesced (consecutive ids); LDS writes at padded stride.
            const int4* gK = reinterpret_cast<const int4*>(Kb + (rbase + (size_t)mc*64)*Cn);
            const int4* gQ = reinterpret_cast<const int4*>(Qb + (rbase + (size_t)mc*64)*Cn);
            #pragma unroll
            for (int i = 0; i < 4; i++){
                int id = i*256 + t;              // 0..1023
                int r = id >> 4, c2 = id & 15;   // row in tile, 16B chunk in row
                int4 vk = gK[id];
                int4 vq = gQ[id];
                *reinterpret_cast<int4*>(&Ks_s[r*LDS_STRIDE + c2*8]) = vk;
                *reinterpret_cast<int4*>(&Qs_s[r*LDS_STRIDE + c2*8]) = vq;
            }
        }
        __syncthreads();
        #pragma unroll
        for (int mt = 0; mt < 4; mt++){
            const int m0 = mc*64 + mt*16;
            bf16x8 bK[4], bQ[4];
            #pragma unroll
            for (int ks = 0; ks < 4; ks++){
                bK[ks] = *as_frag(&Ks_s[(mt*16+lc)*LDS_STRIDE + ks*32 + q*8]);
                bQ[ks] = *as_frag(&Qs_s[(mt*16+lc)*LDS_STRIDE + ks*32 + q*8]);
            }
            // acc[n][m] = Qn.Km + Kn.Qm  (symmetrization folded in)
            f32x4 acc = {0.f,0.f,0.f,0.f};
            #pragma unroll
            for (int ks = 0; ks < 4; ks++){
                acc = __builtin_amdgcn_mfma_f32_16x16x32_bf16(aQ[ks], bK[ks], acc, 0, 0, 0);
                acc = __builtin_amdgcn_mfma_f32_16x16x32_bf16(aK[ks], bQ[ks], acc, 0, 0, 0);
            }
            const int m = m0 + lc;   // C/D col = lane&15
            #pragma unroll
            for (int r = 0; r < 4; r++){
                const int n = nout[r];
                float logit = fmaf(acc[r], SCALE, __half2float(CB[(size_t)n*Nn + m]));
                float e = __expf(logit - SHIFT);   // -inf -> 0
                sumacc[r] += e;
                out[(rbase + n)*Nn + m] = e;       // unnormalized
            }
        }
    }
    #pragma unroll
    for (int r = 0; r < 4; r++){
        float s = sumacc[r];
        s += __shfl_xor(s, 1);
        s += __shfl_xor(s, 2);
        s += __shfl_xor(s, 4);
        s += __shfl_xor(s, 8);
        if (lc == 0) rowsum[rbase + nout[r]] = 1.0f / s;   // store reciprocal
    }
}

// --- pure memory-bound normalization: out[n][m] *= rsinv[n] ---
// 4096 blocks x 256 threads x 16 float4 = exactly B*N*N/4 float4s.
__global__ __launch_bounds__(256) void norm_kernel(
    float* __restrict__ out, const float* __restrict__ rsinv)
{
    const size_t t0 = (size_t)blockIdx.x * 256 + threadIdx.x;
    const size_t stride = (size_t)4096 * 256;
    float4* o4 = reinterpret_cast<float4*>(out);
    #pragma unroll
    for (int i = 0; i < 16; i++){
        size_t idx = t0 + (size_t)i * stride;
        float4 v = o4[idx];
        float r = rsinv[idx >> 9];       // 512 float4s per row
        v.x *= r; v.y *= r; v.z *= r; v.w *= r;
        o4[idx] = v;
    }
}

// ws layout (bytes):
//   [0,        8388608)   Qb   bf16 [B*N, C]
//   [8388608,  16777216)  Kb   bf16 [B*N, C]
//   [16777216, 16908288)  rowsum fp32 [B*N] (holds reciprocals)
//   [16908288, 16973824)  WqT  fp32 [C, C]
//   [16973824, 17039360)  WkT  fp32 [C, C]
//   [17039360, 25427968)  CB   fp16 [N, N]
extern "C" void kernel_launch(void* const* d_in, const int* in_sizes, int n_in,
                              void* d_out, int out_size, void* d_ws, size_t ws_size,
                              hipStream_t stream)
{
    const float* H  = (const float*)d_in[0];
    const float* A  = (const float*)d_in[1];
    const float* M  = (const float*)d_in[2];
    const float* Wq = (const float*)d_in[3];
    const float* Wk = (const float*)d_in[4];
    float* out = (float*)d_out;
    char* ws = (char*)d_ws;
    __hip_bfloat16* Qb = (__hip_bfloat16*)(ws + 0);
    __hip_bfloat16* Kb = (__hip_bfloat16*)(ws + 8388608);
    float* rowsum      = (float*)(ws + 16777216);
    float* WqT         = (float*)(ws + 16908288);
    float* WkT         = (float*)(ws + 16973824);
    __half* CB         = (__half*)(ws + 17039360);

    prep_kernel<<<(Nn*Nn)/256, 256, 0, stream>>>(A, M, CB, Wq, Wk, WqT, WkT);
    qk_kernel<<<(Bn*Nn)/32, 256, 0, stream>>>(H, WqT, WkT, Qb, Kb);
    attn_e_kernel<<<dim3(Nn/64, Bn), 256, 0, stream>>>(Qb, Kb, CB, rowsum, out);
    norm_kernel<<<4096, 256, 0, stream>>>(out, rowsum);
}

// Round 2
// 455.641 us; speedup vs baseline: 1.1213x; 1.1213x over previous
//
#include <hip/hip_runtime.h>
#include <hip/hip_bf16.h>
#include <hip/hip_fp16.h>
#include <math.h>

#define Bn 16
#define Nn 2048
#define Cn 128

typedef __attribute__((ext_vector_type(8))) short bf16x8;   // 8 bf16 = 4 VGPRs
typedef __attribute__((ext_vector_type(4))) float f32x4;

// 0.5 / (sqrt(128) * 1.5)  -- folds symmetrization 0.5 and temperature
constexpr float SCALE = 0.029462782549439476f;
constexpr float SHIFT = 4.0f;  // fixed softmax shift; logits bounded well below this +88

__device__ __forceinline__ const bf16x8* as_frag(const void* p){
    return reinterpret_cast<const bf16x8*>(p);
}

// async global->LDS, 16B per lane. LDS dest = wave-uniform base + lane*16 (HW).
__device__ __forceinline__ void load16_lds(const void* g, void* l){
    __builtin_amdgcn_global_load_lds(
        (const __attribute__((address_space(1))) void*)g,
        (__attribute__((address_space(3))) void*)l,
        16, 0, 0);
}

// --- fused prep: combined bias (fp16) for all blocks; first 64 blocks also
//     transpose W [d][c] -> WT [c][d] so the projection kernel reads coalesced.
__global__ __launch_bounds__(256) void prep_kernel(
    const float* __restrict__ A, const float* __restrict__ M, __half* __restrict__ CB,
    const float* __restrict__ Wq, const float* __restrict__ Wk,
    float* __restrict__ WqT, float* __restrict__ WkT)
{
    size_t idx = (size_t)blockIdx.x * 256 + threadIdx.x;
    int n = (int)(idx >> 11), m = (int)(idx & (Nn-1));
    float a = A[idx];
    float mm = M[idx];
    float v = (mm <= 0.0f || n == m) ? -INFINITY : a;
    CB[idx] = __float2half(v);
    if (blockIdx.x < 64) {
        int widx = (int)idx;            // 0..16383
        int d = widx >> 7, c = widx & 127;
        WqT[c*Cn + d] = Wq[widx];
        WkT[c*Cn + d] = Wk[widx];
    }
}

// --- Q/K projection: fp32 accumulate, bf16 store. 32 rows per block. ---
__global__ __launch_bounds__(256) void qk_kernel(
    const float* __restrict__ H, const float* __restrict__ WqT, const float* __restrict__ WkT,
    __hip_bfloat16* __restrict__ Qb, __hip_bfloat16* __restrict__ Kb)
{
    __shared__ __align__(16) float Hs[32*Cn];
    const int t = threadIdx.x;
    const size_t row0 = (size_t)blockIdx.x * 32;
    const float4* src = reinterpret_cast<const float4*>(H + row0*Cn);
    float4* dst = reinterpret_cast<float4*>(Hs);
    #pragma unroll
    for (int i = 0; i < 4; i++) dst[i*256 + t] = src[i*256 + t];
    __syncthreads();
    const int d = t & 127, rh = t >> 7;
    float accq[16], acck[16];
    #pragma unroll
    for (int r = 0; r < 16; r++){ accq[r] = 0.f; acck[r] = 0.f; }
    for (int cb = 0; cb < Cn; cb += 4){
        float wq[4], wk[4];
        #pragma unroll
        for (int j = 0; j < 4; j++){ wq[j] = WqT[(cb+j)*Cn + d]; wk[j] = WkT[(cb+j)*Cn + d]; }
        #pragma unroll
        for (int r = 0; r < 16; r++){
            float4 h = *reinterpret_cast<const float4*>(&Hs[(rh*16+r)*Cn + cb]);
            accq[r] += h.x*wq[0] + h.y*wq[1] + h.z*wq[2] + h.w*wq[3];
            acck[r] += h.x*wk[0] + h.y*wk[1] + h.z*wk[2] + h.w*wk[3];
        }
    }
    #pragma unroll
    for (int r = 0; r < 16; r++){
        size_t row = row0 + rh*16 + r;
        Qb[row*Cn + d] = __float2bfloat16(accq[r]);
        Kb[row*Cn + d] = __float2bfloat16(acck[r]);
    }
}

// --- main attention, 2-pass (PASS 0: partial row sums; PASS 1: write probs) ---
// Block = 256 threads = 4 waves. Block tile = 128 rows x 1024 cols (half of m).
// Each wave owns 32 rows (2 row-groups of 16). Grid x = 16 rowblocks * 2 colhalves.
// LDS: linear [64 rows][256 B] K and Q tiles, contents XOR-swizzled per row:
//   LDS[row][cw] (16B chunks, cw 0..15) holds global chunk (row, cw ^ (row&7)).
// Staged via global_load_lds (linear dest) from pre-swizzled global addresses;
// ds_read_b128 applies the same XOR -> conflict-free (8 dwords/bank, optimal).
template<int PASS>
__global__ __launch_bounds__(256) void attn_kernel(
    const __hip_bfloat16* __restrict__ Qb, const __hip_bfloat16* __restrict__ Kb,
    const __half* __restrict__ CB, float* __restrict__ rowsum, float* __restrict__ out)
{
    __shared__ __align__(16) char Ks_s[64*256];
    __shared__ __align__(16) char Qs_s[64*256];
    const int t = threadIdx.x;
    const int wave = t >> 6, lane = t & 63;
    const int q = lane >> 4, lc = lane & 15;
    const int rb = blockIdx.x & 15, ch = blockIdx.x >> 4;
    const int batch = blockIdx.y;
    const int n0 = rb * 128;
    const size_t rbase = (size_t)batch * Nn;

    // A-operand fragments: 2 row-groups of 16 rows; lane holds row lc, k = ks*32+q*8..+7
    bf16x8 aQ[2][4], aK[2][4];
    #pragma unroll
    for (int g = 0; g < 2; g++){
        const int nA = n0 + wave*32 + g*16 + lc;
        #pragma unroll
        for (int ks = 0; ks < 4; ks++){
            aQ[g][ks] = *as_frag(Qb + (rbase + nA)*Cn + ks*32 + q*8);
            aK[g][ks] = *as_frag(Kb + (rbase + nA)*Cn + ks*32 + q*8);
        }
    }

    int nout[2][4];
    #pragma unroll
    for (int g = 0; g < 2; g++)
        #pragma unroll
        for (int r = 0; r < 4; r++) nout[g][r] = n0 + wave*32 + g*16 + q*4 + r;

    float rs_inv[2][4];
    if (PASS == 1){
        #pragma unroll
        for (int g = 0; g < 2; g++)
            #pragma unroll
            for (int r = 0; r < 4; r++){
                float s = rowsum[rbase + nout[g][r]] + rowsum[(size_t)Bn*Nn + rbase + nout[g][r]];
                rs_inv[g][r] = 1.0f / s;
            }
    }

    float sumacc[2][4] = {{0.f,0.f,0.f,0.f},{0.f,0.f,0.f,0.f}};

    // staging lane constants: issue idx covers 4 rows (64 chunks); lane -> row idx*4+(lane>>4),
    // chunk cw = lane&15; src chunk = cw ^ (row&7) = cw ^ (lane>>4) ^ (4*(idx&1))
    const int laneoffE = ((lane >> 4) << 8) + ((((lane & 15) ^ (lane >> 4))) << 4);
    // read-side lane constants: chunk(ks) = (4*ks + q) ^ (lc&7)
    int coff[4];
    #pragma unroll
    for (int ks = 0; ks < 4; ks++) coff[ks] = (((4*ks + q) ^ (lc & 7)) << 4);
    const int rowoff = lc * 256;

    const char* gkb = (const char*)Kb;
    const char* gqb = (const char*)Qb;
    const char* gt0 = (wave < 2) ? gkb : gqb;
    void* lt = (wave < 2) ? (void*)Ks_s : (void*)Qs_s;
    const int idx0 = (wave & 1) * 8;

    const int mc0 = ch * (Nn/128);          // 16 mc iters per block
    for (int mc = mc0; mc < mc0 + Nn/128; mc++){
        __syncthreads();   // prev iter's LDS reads done before overwrite
        {   // stage 64 m-rows of K and Q (16 KB each = 16 x 1KB issues, 8 per wave)
            const size_t tileoff = (rbase + (size_t)mc*64) * (Cn*2);
            const char* gt = gt0 + tileoff;
            #pragma unroll
            for (int j = 0; j < 8; j++){
                const int idx = idx0 + j;
                const int lo = laneoffE ^ ((j & 1) << 6);   // idx&1 == j&1 (idx0 even)
                load16_lds(gt + idx*1024 + lo, (char*)lt + idx*1024);
            }
        }
        __syncthreads();   // implies vmcnt(0): staged data visible
        #pragma unroll
        for (int mt = 0; mt < 4; mt++){
            const int m0 = mc*64 + mt*16;
            bf16x8 bK[4], bQ[4];
            #pragma unroll
            for (int ks = 0; ks < 4; ks++){
                bK[ks] = *as_frag(Ks_s + mt*4096 + rowoff + coff[ks]);
                bQ[ks] = *as_frag(Qs_s + mt*4096 + rowoff + coff[ks]);
            }
            const int m = m0 + lc;   // C/D col = lane&15
            #pragma unroll
            for (int g = 0; g < 2; g++){
                // acc[n][m] = Qn.Km + Kn.Qm  (symmetrization folded in)
                f32x4 acc = {0.f,0.f,0.f,0.f};
                #pragma unroll
                for (int ks = 0; ks < 4; ks++){
                    acc = __builtin_amdgcn_mfma_f32_16x16x32_bf16(aQ[g][ks], bK[ks], acc, 0, 0, 0);
                    acc = __builtin_amdgcn_mfma_f32_16x16x32_bf16(aK[g][ks], bQ[ks], acc, 0, 0, 0);
                }
                #pragma unroll
                for (int r = 0; r < 4; r++){
                    const int n = nout[g][r];
                    float logit = fmaf(acc[r], SCALE, __half2float(CB[(size_t)n*Nn + m]));
                    float e = __expf(logit - SHIFT);   // -inf -> 0
                    if (PASS == 0) sumacc[g][r] += e;
                    else out[(rbase + n)*Nn + m] = e * rs_inv[g][r];
                }
            }
        }
    }
    if (PASS == 0){
        float* rs = rowsum + (size_t)ch * (Bn*Nn);   // per-colhalf partial sums
        #pragma unroll
        for (int g = 0; g < 2; g++)
            #pragma unroll
            for (int r = 0; r < 4; r++){
                float s = sumacc[g][r];
                s += __shfl_xor(s, 1);
                s += __shfl_xor(s, 2);
                s += __shfl_xor(s, 4);
                s += __shfl_xor(s, 8);
                if (lc == 0) rs[rbase + nout[g][r]] = s;
            }
    }
}

// ws layout (bytes):
//   [0,        8388608)   Qb   bf16 [B*N, C]
//   [8388608,  16777216)  Kb   bf16 [B*N, C]
//   [16777216, 17825792)  rowsum fp32 [2][B*N]  (per-colhalf partials)
//   [17825792, 17891328)  WqT  fp32 [C, C]
//   [17891328, 17956864)  WkT  fp32 [C, C]
//   [17956864, 26345472)  CB   fp16 [N, N]
extern "C" void kernel_launch(void* const* d_in, const int* in_sizes, int n_in,
                              void* d_out, int out_size, void* d_ws, size_t ws_size,
                              hipStream_t stream)
{
    const float* H  = (const float*)d_in[0];
    const float* A  = (const float*)d_in[1];
    const float* M  = (const float*)d_in[2];
    const float* Wq = (const float*)d_in[3];
    const float* Wk = (const float*)d_in[4];
    float* out = (float*)d_out;
    char* ws = (char*)d_ws;
    __hip_bfloat16* Qb = (__hip_bfloat16*)(ws + 0);
    __hip_bfloat16* Kb = (__hip_bfloat16*)(ws + 8388608);
    float* rowsum      = (float*)(ws + 16777216);
    float* WqT         = (float*)(ws + 17825792);
    float* WkT         = (float*)(ws + 17891328);
    __half* CB         = (__half*)(ws + 17956864);

    prep_kernel<<<(Nn*Nn)/256, 256, 0, stream>>>(A, M, CB, Wq, Wk, WqT, WkT);
    qk_kernel<<<(Bn*Nn)/32, 256, 0, stream>>>(H, WqT, WkT, Qb, Kb);
    attn_kernel<0><<<dim3(32, Bn), 256, 0, stream>>>(Qb, Kb, CB, rowsum, out);
    attn_kernel<1><<<dim3(32, Bn), 256, 0, stream>>>(Qb, Kb, CB, rowsum, out);
}